// Round 1
// baseline (609.531 us; speedup 1.0000x reference)
//
#include <hip/hip_runtime.h>
#include <cstddef>
#include <cstdint>

// ---- problem constants ----
#define B_ROWS 8192   // batch
#define K_DIM  2048   // IN_CH
#define N_GATE 2048   // OUT_CH (per gate)
#define NG     4      // gates: f, i, o, s
#define W_COLS (NG * N_GATE)  // 8192

// ---- GEMM tile config (m97-structure) ----
#define BM  128       // batch rows per block
#define BGN 64        // gate-space cols per block
#define BK  32        // K per step
#define KT  (K_DIM / BK)  // 64 steps

typedef __attribute__((ext_vector_type(8))) short s16x8;   // 8 bf16 (4 VGPR)
typedef __attribute__((ext_vector_type(4))) short s16x4;
typedef __attribute__((ext_vector_type(4))) float f32x4;

__device__ __forceinline__ float fast_sigmoid(float x) {
  return 1.0f / (1.0f + __expf(-x));
}
__device__ __forceinline__ float fast_tanh(float x) {
  return 1.0f - 2.0f / (__expf(2.0f * x) + 1.0f);
}

// ---------------- prep kernel 1: input f32 -> bf16 (same layout) ----------------
__global__ void convert_in_kernel(const float4* __restrict__ src,
                                  s16x4* __restrict__ dst, int n4) {
  int idx = blockIdx.x * blockDim.x + threadIdx.x;
  int stride = gridDim.x * blockDim.x;
  for (int i = idx; i < n4; i += stride) {
    float4 v = src[i];
    s16x4 o = { __builtin_bit_cast(short, (__bf16)v.x),
                __builtin_bit_cast(short, (__bf16)v.y),
                __builtin_bit_cast(short, (__bf16)v.z),
                __builtin_bit_cast(short, (__bf16)v.w) };
    dst[i] = o;
  }
}

// ---------------- prep kernel 2: W [K][4N] f32 -> Wt [4N][K] bf16 ----------------
__global__ void convert_w_kernel(const float* __restrict__ W,
                                 short* __restrict__ Wt) {
  __shared__ float tile[32][33];
  int n0 = blockIdx.x * 32;   // along 8192 (gate cols)
  int k0 = blockIdx.y * 32;   // along 2048 (K)
  int tx = threadIdx.x, ty = threadIdx.y;  // 32 x 8
#pragma unroll
  for (int j = 0; j < 32; j += 8)
    tile[ty + j][tx] = W[(size_t)(k0 + ty + j) * W_COLS + n0 + tx];
  __syncthreads();
#pragma unroll
  for (int j = 0; j < 32; j += 8)
    Wt[(size_t)(n0 + ty + j) * K_DIM + k0 + tx] =
        __builtin_bit_cast(short, (__bf16)tile[tx][ty + j]);
}

// ---------------- main fused GEMM + LSTM epilogue ----------------
// A: [8192][2048] bf16, Wt: [8192][2048] bf16 (row g*2048+n = W column g*2048+n)
// Each block: 128 batch rows x 64 gate cols, 4 gate accumulators.
// 4 waves as 2x2 -> wave tile 64x32 per gate; frags 4(m) x 2(n) per gate.
//
// LDS tiles are built of 16B granules (8 bf16). Swizzle: for tile-local row r,
// logical granule g lives at physical granule g ^ ((r>>1)&3). Staging writes
// linearly (global_load_lds requirement) with pre-swizzled SOURCE address;
// ds_read applies the same XOR -> 2-way bank aliasing (free, m136).
#define GL16(gsrc, ldst)                                                        \
  __builtin_amdgcn_global_load_lds(                                             \
      (const __attribute__((address_space(1))) unsigned int*)(gsrc),            \
      (__attribute__((address_space(3))) unsigned int*)(ldst), 16, 0, 0)

__global__ __launch_bounds__(256, 2) void lstm_gemm_kernel(
    const short* __restrict__ Abf,   // bf16 bits
    const short* __restrict__ Wt,    // bf16 bits
    const float* __restrict__ bias,  // [8192]
    const float* __restrict__ cell,  // [8192][2048]
    float* __restrict__ outH,        // [8192][2048]
    float* __restrict__ outC) {      // [8192][2048]
  __shared__ short As[2][BM * BK];        // 2 x 8 KiB
  __shared__ short Bs[2][NG * BGN * BK];  // 2 x 16 KiB

  const int tid = threadIdx.x;
  const int lane = tid & 63;
  const int wid = tid >> 6;
  const int wm = wid >> 1;   // 0..1 (m)
  const int wn = wid & 1;    // 0..1 (n)
  const int lrow = lane & 15;
  const int lk = lane >> 4;  // k-octet 0..3

  // XCD-band decode: XCD x owns gate-col tiles [x*4, x*4+4) for all m-tiles.
  const int bid = blockIdx.x;
  const int x = bid & 7;
  const int ii = bid >> 3;         // 0..255
  const int tn = x * 4 + (ii & 3); // 0..31
  const int tm = ii >> 2;          // 0..63
  const int m0 = tm * BM;
  const int n0 = tn * BGN;

  f32x4 acc[NG][4][2];
#pragma unroll
  for (int g = 0; g < NG; ++g)
#pragma unroll
    for (int mi = 0; mi < 4; ++mi)
#pragma unroll
      for (int ni = 0; ni < 2; ++ni)
        acc[g][mi][ni] = (f32x4){0.f, 0.f, 0.f, 0.f};

  // precompute fragment LDS byte offsets (swizzled)
  int a_off[4];
#pragma unroll
  for (int mi = 0; mi < 4; ++mi) {
    int ar = wm * 64 + mi * 16 + lrow;
    a_off[mi] = (ar * 4 + (lk ^ ((ar >> 1) & 3))) * 16;
  }
  int b_off[NG][2];
#pragma unroll
  for (int g = 0; g < NG; ++g)
#pragma unroll
    for (int ni = 0; ni < 2; ++ni) {
      int br = wn * 32 + ni * 16 + lrow;
      b_off[g][ni] = (g * 256 + br * 4 + (lk ^ ((br >> 1) & 3))) * 16;
    }

  auto stage = [&](int buf, int kk) {
    // A tile: 128 rows x 4 granules = 512 units, 2 block-wide ops
#pragma unroll
    for (int j = 0; j < 2; ++j) {
      int p = j * 256 + tid;
      int row = p >> 2;
      int gl = (p & 3) ^ ((p >> 3) & 3);  // inverse swizzle on SOURCE
      GL16(Abf + (size_t)(m0 + row) * K_DIM + kk + gl * 8, &As[buf][p * 8]);
    }
    // B tiles: per gate 64 rows x 4 granules = 256 units, 1 op each
#pragma unroll
    for (int g = 0; g < NG; ++g) {
      int row = tid >> 2;
      int gl = (tid & 3) ^ ((tid >> 3) & 3);
      GL16(Wt + (size_t)(g * N_GATE + n0 + row) * K_DIM + kk + gl * 8,
           &Bs[buf][(g * 256 + tid) * 8]);
    }
  };

  stage(0, 0);
  __syncthreads();

  for (int kt = 0; kt < KT; ++kt) {
    const int cur = kt & 1;
    if (kt + 1 < KT) stage(cur ^ 1, (kt + 1) * BK);

    const char* abase = (const char*)As[cur];
    const char* bbase = (const char*)Bs[cur];
    s16x8 af[4];
#pragma unroll
    for (int mi = 0; mi < 4; ++mi)
      af[mi] = *reinterpret_cast<const s16x8*>(abase + a_off[mi]);
#pragma unroll
    for (int g = 0; g < NG; ++g) {
      s16x8 bf0 = *reinterpret_cast<const s16x8*>(bbase + b_off[g][0]);
      s16x8 bf1 = *reinterpret_cast<const s16x8*>(bbase + b_off[g][1]);
#pragma unroll
      for (int mi = 0; mi < 4; ++mi) {
        acc[g][mi][0] = __builtin_amdgcn_mfma_f32_16x16x32_bf16(
            af[mi], bf0, acc[g][mi][0], 0, 0, 0);
        acc[g][mi][1] = __builtin_amdgcn_mfma_f32_16x16x32_bf16(
            af[mi], bf1, acc[g][mi][1], 0, 0, 0);
      }
    }
    __syncthreads();
  }

  // ---- fused LSTM epilogue ----
  // C/D layout: col = lane&15 (gate col), row = (lane>>4)*4 + reg (batch row)
#pragma unroll
  for (int ni = 0; ni < 2; ++ni) {
    const int n = n0 + wn * 32 + ni * 16 + lrow;
    const float bf_ = bias[n];
    const float bi_ = bias[N_GATE + n];
    const float bo_ = bias[2 * N_GATE + n];
    const float bs_ = bias[3 * N_GATE + n];
#pragma unroll
    for (int mi = 0; mi < 4; ++mi) {
#pragma unroll
      for (int r = 0; r < 4; ++r) {
        const int m = m0 + wm * 64 + mi * 16 + lk * 4 + r;
        const size_t off = (size_t)m * N_GATE + n;
        const float fg = fast_sigmoid(acc[0][mi][ni][r] + bf_);
        const float ig = fast_sigmoid(acc[1][mi][ni][r] + bi_);
        const float og = fast_sigmoid(acc[2][mi][ni][r] + bo_);
        const float sg = fast_sigmoid(acc[3][mi][ni][r] + bs_);
        const float cn = fg * cell[off] + ig * sg;
        outC[off] = cn;
        outH[off] = og * fast_tanh(cn);
      }
    }
  }
}

extern "C" void kernel_launch(void* const* d_in, const int* in_sizes, int n_in,
                              void* d_out, int out_size, void* d_ws, size_t ws_size,
                              hipStream_t stream) {
  const float* inp  = (const float*)d_in[0];
  // d_in[1] = hidden: UNUSED by the reference computation
  const float* cell = (const float*)d_in[2];
  const float* W    = (const float*)d_in[3];
  const float* bias = (const float*)d_in[4];

  float* outH = (float*)d_out;
  float* outC = (float*)d_out + (size_t)B_ROWS * N_GATE;

  short* Abf = (short*)d_ws;                                  // 32 MiB
  short* Wt  = (short*)d_ws + (size_t)B_ROWS * K_DIM;         // 32 MiB

  // 1) input -> bf16
  {
    int n4 = (B_ROWS * K_DIM) / 4;
    convert_in_kernel<<<2048, 256, 0, stream>>>((const float4*)inp,
                                                (s16x4*)Abf, n4);
  }
  // 2) W -> Wt (transpose + bf16)
  {
    dim3 grid(W_COLS / 32, K_DIM / 32);
    dim3 block(32, 8);
    convert_w_kernel<<<grid, block, 0, stream>>>(W, Wt);
  }
  // 3) fused GEMM + gates
  {
    int nblocks = (B_ROWS / BM) * (N_GATE / BGN);  // 64 * 32 = 2048
    lstm_gemm_kernel<<<nblocks, 256, 0, stream>>>(Abf, Wt, bias, cell,
                                                  outH, outC);
  }
}

// Round 6
// 536.843 us; speedup vs baseline: 1.1354x; 1.1354x over previous
//
#include <hip/hip_runtime.h>
#include <cstddef>
#include <cstdint>

// ---- problem constants ----
#define B_ROWS 8192   // batch
#define K_DIM  2048   // IN_CH
#define N_GATE 2048   // OUT_CH (per gate)
#define NG     4      // gates: f, i, o, s
#define W_COLS (NG * N_GATE)  // 8192

// ---- GEMM tile config (m201 8-phase 256^2 template) ----
#define BM   256      // batch rows per block
#define BK   64       // K per tile
#define NTIL 32       // K_DIM / BK

typedef __attribute__((ext_vector_type(8))) short s16x8;   // 8 bf16
typedef __attribute__((ext_vector_type(4))) float f32x4;

__device__ __forceinline__ float fast_sigmoid(float x) {
  return 1.0f / (1.0f + __expf(-x));
}
__device__ __forceinline__ float fast_tanh(float x) {
  return 1.0f - 2.0f / (__expf(2.0f * x) + 1.0f);
}

// ---------------- prep kernel 1: input f32 -> bf16 (16B stores) ----------------
__global__ void convert_in_kernel(const float4* __restrict__ src,
                                  s16x8* __restrict__ dst, int n8) {
  int idx = blockIdx.x * blockDim.x + threadIdx.x;
  int stride = gridDim.x * blockDim.x;
  for (int i = idx; i < n8; i += stride) {
    float4 a = src[2 * i], b = src[2 * i + 1];
    s16x8 o = { __builtin_bit_cast(short, (__bf16)a.x),
                __builtin_bit_cast(short, (__bf16)a.y),
                __builtin_bit_cast(short, (__bf16)a.z),
                __builtin_bit_cast(short, (__bf16)a.w),
                __builtin_bit_cast(short, (__bf16)b.x),
                __builtin_bit_cast(short, (__bf16)b.y),
                __builtin_bit_cast(short, (__bf16)b.z),
                __builtin_bit_cast(short, (__bf16)b.w) };
    dst[i] = o;
  }
}

// ---------------- prep kernel 2: W [K][4N] f32 -> Wt [4N][K] bf16 ----------------
// 64x64 tile per block. LDS: 32-bit words [k 0..63][np 0..31], word np stored at
// slot np^(k&31). Read: coalesced 64B/lane float4 runs. Write: 8-lane groups
// store 128B contiguous output rows (two 16B stores per thread).
__device__ __forceinline__ unsigned int pack2bf16(float x, float y) {
  unsigned short lo = __builtin_bit_cast(unsigned short, (__bf16)x);
  unsigned short hi = __builtin_bit_cast(unsigned short, (__bf16)y);
  return ((unsigned int)hi << 16) | lo;
}

__global__ __launch_bounds__(256) void convert_w_kernel(const float* __restrict__ W,
                                                        short* __restrict__ Wt) {
  __shared__ unsigned int tile[64 * 32];  // 8 KiB
  const int t = threadIdx.x;
  const int n0 = blockIdx.x * 64;   // along 8192 gate-cols
  const int k0 = blockIdx.y * 64;   // along 2048 K
  {
    const int kr = t >> 2, seg = t & 3;
    const float4* src = (const float4*)(W + (size_t)(k0 + kr) * W_COLS + n0 + seg * 16);
#pragma unroll
    for (int u = 0; u < 4; ++u) {
      float4 v = src[u];
      const int np = seg * 8 + u * 2;
      tile[kr * 32 + (np ^ (kr & 31))]       = pack2bf16(v.x, v.y);
      tile[kr * 32 + ((np + 1) ^ (kr & 31))] = pack2bf16(v.z, v.w);
    }
  }
  __syncthreads();
  {
    const int np = t >> 3;   // column pair 0..31 -> output rows n0+2np, +1
    const int kb = t & 7;    // k-block of 8
    unsigned int w[8];
#pragma unroll
    for (int v = 0; v < 8; ++v) {
      const int k = kb * 8 + v;
      w[v] = tile[k * 32 + (np ^ (k & 31))];
    }
    s16x8 lo, hi;
#pragma unroll
    for (int v = 0; v < 8; ++v) {
      lo[v] = (short)(w[v] & 0xffff);
      hi[v] = (short)(w[v] >> 16);
    }
    short* d0 = Wt + (size_t)(n0 + 2 * np) * K_DIM + k0 + kb * 8;
    *(s16x8*)d0 = lo;
    *(s16x8*)(d0 + K_DIM) = hi;
  }
}

// ---------------- main fused GEMM + LSTM epilogue (8-phase template) ----------------
// Block: 256 batch rows x 64 actual cols x 4 gates (gate-space 256x256), BK=64.
// 8 waves = 2(m) x 4(n16). Per wave: 128 m-rows x 16 actual cols x 4 gates
//   -> acc[8 mi][4 gates] f32x4 (128 VGPR). n-frag j == gate j -> LSTM math in-wave.
// LDS: As[2][256][64] + Bs[2][256][64] bf16 = 128 KiB dynamic.
// 16B granules XOR-swizzled: phys = logical ^ (row&7); staging uses linear LDS
// dest + inverse-swizzled GLOBAL source (both-sides rule; row&7 == lrow&7 on
// the read side since all row-offset terms are multiples of 8).
//
// Iteration i reads T0=2i from buf0 (ph1-4) and T1=2i+1 from buf1 (ph5-8).
// Stage slots (race-free: buf0-A reads end ph4; buf1-A reads end prev ph8;
// buf0-B reads end ph1; buf1-B reads end ph5):
//   ph1: A(T1)h0 -> buf1     ph5: A(T0+2)h0 -> buf0
//   ph2: A(T1)h1 -> buf1     ph6: A(T0+2)h1 -> buf0
//   ph3: B(T0+2)h0 -> buf0   ph7: B(T1+2)h0 -> buf1
//   ph4: B(T0+2)h1 -> buf0   ph8: B(T1+2)h1 -> buf1
// vmcnt(4) at ph4 (retires A(T1), read ph5+) and ph8 (retires tile T0+2, read
// next ph1). Ledger: loop-top outstanding = 4 (next buf1-B); 12 peak; never 0.
// Tail (i=15): ph1,2 stage A(31); ph4 vmcnt(0); no other stages.
#define GL16(gsrc, ldst)                                                        \
  __builtin_amdgcn_global_load_lds(                                             \
      (const __attribute__((address_space(1))) unsigned int*)(gsrc),            \
      (__attribute__((address_space(3))) unsigned int*)(ldst), 16, 0, 0)

#define MFMA16 __builtin_amdgcn_mfma_f32_16x16x32_bf16

__global__ __launch_bounds__(512, 2) void lstm_gemm_kernel(
    const short* __restrict__ Abf,   // bf16 [8192][2048]
    const short* __restrict__ Wt,    // bf16 [8192][2048]
    const float* __restrict__ bias,  // [8192]
    const float* __restrict__ cell,  // [8192][2048]
    float* __restrict__ outH,        // [8192][2048]
    float* __restrict__ outC) {      // [8192][2048]
  extern __shared__ short lds[];     // As: shorts [0,32768); Bs: [32768,65536)

  const int tid = threadIdx.x;
  const int lane = tid & 63;
  const int wid = tid >> 6;
  const int wm = wid >> 2;   // 0..1
  const int wn = wid & 3;    // 0..3
  const int lrow = lane & 15;
  const int lk = lane >> 4;  // 0..3

  // XCD-banded swizzle: XCD x owns tn in [x*4, x*4+4), tm sweeps within.
  const int bid = blockIdx.x;
  const int xcd = bid & 7, j = bid >> 3;
  const int tn = xcd * 4 + (j >> 5);  // 0..31
  const int tm = j & 31;              // 0..31
  const int m0 = tm * BM;
  const int n0 = tn * 64;

  // ---- staging sources: physical granule p = h*1024 + jj*512 + tid ----
  size_t a_src[2][2], b_src[2][2];
#pragma unroll
  for (int h = 0; h < 2; ++h)
#pragma unroll
    for (int jj = 0; jj < 2; ++jj) {
      const int p = h * 1024 + jj * 512 + tid;
      const int r = p >> 3;                 // tile row 0..255
      const int gl = (p & 7) ^ (r & 7);     // inverse swizzle on SOURCE
      a_src[h][jj] = (size_t)(m0 + r) * K_DIM + gl * 8;
      const int wn16 = r >> 6, g = (r >> 4) & 3, nc4 = r & 15;
      b_src[h][jj] = (size_t)(g * N_GATE + n0 + wn16 * 16 + nc4) * K_DIM + gl * 8;
    }

#define STAGE_A(BUF, H, KT) do {                                                 \
    GL16(Abf + a_src[H][0] + (size_t)(KT) * BK,                                  \
         lds + (BUF) * 16384 + ((H) * 1024 + tid) * 8);                          \
    GL16(Abf + a_src[H][1] + (size_t)(KT) * BK,                                  \
         lds + (BUF) * 16384 + ((H) * 1024 + 512 + tid) * 8);                    \
  } while (0)
#define STAGE_B(BUF, H, KT) do {                                                 \
    GL16(Wt + b_src[H][0] + (size_t)(KT) * BK,                                   \
         lds + 32768 + (BUF) * 16384 + ((H) * 1024 + tid) * 8);                  \
    GL16(Wt + b_src[H][1] + (size_t)(KT) * BK,                                   \
         lds + 32768 + (BUF) * 16384 + ((H) * 1024 + 512 + tid) * 8);            \
  } while (0)

  // ---- fragment read bases (byte offsets; granule-swizzled) ----
  const int pg0 = (lk ^ (lrow & 7)) * 16;        // kk=0 physical granule byte
  const int pg1 = ((4 + lk) ^ (lrow & 7)) * 16;  // kk=1
  const char* aK0 = (const char*)lds + (wm * 128 + lrow) * 128 + pg0;
  const char* aK1 = (const char*)lds + (wm * 128 + lrow) * 128 + pg1;
  const char* bK0 = (const char*)lds + 65536 + (wn * 64 + lrow) * 128 + pg0;
  const char* bK1 = (const char*)lds + 65536 + (wn * 64 + lrow) * 128 + pg1;
#define AF(BUF, MI, KK) (*(const s16x8*)(aK##KK + (BUF) * 32768 + (MI) * 2048))
#define BFR(BUF, G, KK) (*(const s16x8*)(bK##KK + (BUF) * 32768 + (G) * 2048))

  f32x4 acc[8][4];
#pragma unroll
  for (int mi = 0; mi < 8; ++mi)
#pragma unroll
    for (int g = 0; g < 4; ++g) acc[mi][g] = (f32x4){0.f, 0.f, 0.f, 0.f};

  s16x8 bfr[4][2];

#define MMQ(MI, A0, A1) do {                                                     \
    acc[MI][0] = MFMA16(A0, bfr[0][0], acc[MI][0], 0, 0, 0);                     \
    acc[MI][0] = MFMA16(A1, bfr[0][1], acc[MI][0], 0, 0, 0);                     \
    acc[MI][1] = MFMA16(A0, bfr[1][0], acc[MI][1], 0, 0, 0);                     \
    acc[MI][1] = MFMA16(A1, bfr[1][1], acc[MI][1], 0, 0, 0);                     \
    acc[MI][2] = MFMA16(A0, bfr[2][0], acc[MI][2], 0, 0, 0);                     \
    acc[MI][2] = MFMA16(A1, bfr[2][1], acc[MI][2], 0, 0, 0);                     \
    acc[MI][3] = MFMA16(A0, bfr[3][0], acc[MI][3], 0, 0, 0);                     \
    acc[MI][3] = MFMA16(A1, bfr[3][1], acc[MI][3], 0, 0, 0);                     \
  } while (0)

#define VM_NONE do {} while (0)
#define VM_4 asm volatile("s_waitcnt vmcnt(4)" ::: "memory")
#define VM_0 asm volatile("s_waitcnt vmcnt(0)" ::: "memory")

#define PHASE(BUF, Q, LOADB, STG, VM) do {                                       \
    if (LOADB) {                                                                 \
      bfr[0][0] = BFR(BUF, 0, 0); bfr[0][1] = BFR(BUF, 0, 1);                    \
      bfr[1][0] = BFR(BUF, 1, 0); bfr[1][1] = BFR(BUF, 1, 1);                    \
      bfr[2][0] = BFR(BUF, 2, 0); bfr[2][1] = BFR(BUF, 2, 1);                    \
      bfr[3][0] = BFR(BUF, 3, 0); bfr[3][1] = BFR(BUF, 3, 1);                    \
    }                                                                            \
    s16x8 af00 = AF(BUF, 2 * (Q), 0), af01 = AF(BUF, 2 * (Q), 1);                \
    s16x8 af10 = AF(BUF, 2 * (Q) + 1, 0), af11 = AF(BUF, 2 * (Q) + 1, 1);        \
    STG;                                                                         \
    VM;                                                                          \
    __builtin_amdgcn_s_barrier();                                                \
    asm volatile("s_waitcnt lgkmcnt(0)" ::: "memory");                           \
    __builtin_amdgcn_s_setprio(1);                                               \
    MMQ(2 * (Q), af00, af01);                                                    \
    MMQ(2 * (Q) + 1, af10, af11);                                                \
    __builtin_amdgcn_s_setprio(0);                                               \
    __builtin_amdgcn_s_barrier();                                                \
  } while (0)

  // ---- prologue: tile0 full -> buf0 (8 loads); tile1 B -> buf1 (4 loads) ----
  STAGE_B(0, 0, 0); STAGE_B(0, 1, 0); STAGE_A(0, 0, 0); STAGE_A(0, 1, 0);
  STAGE_B(1, 0, 1); STAGE_B(1, 1, 1);
  VM_4;  // tile0's 8 loads retired; tile1 B (4) in flight
  __builtin_amdgcn_s_barrier();

  // ---- main loop: i = 0..14 (tiles 0..29 + staging up to tile 31) ----
  for (int i = 0; i < NTIL / 2 - 1; ++i) {
    const int t1 = 2 * i + 1, t2 = 2 * i + 2, t3 = 2 * i + 3;
    PHASE(0, 0, 1, { STAGE_A(1, 0, t1); }, VM_NONE);
    PHASE(0, 1, 0, { STAGE_A(1, 1, t1); }, VM_NONE);
    PHASE(0, 2, 0, { STAGE_B(0, 0, t2); }, VM_NONE);
    PHASE(0, 3, 0, { STAGE_B(0, 1, t2); }, VM_4);
    PHASE(1, 0, 1, { STAGE_A(0, 0, t2); }, VM_NONE);
    PHASE(1, 1, 0, { STAGE_A(0, 1, t2); }, VM_NONE);
    PHASE(1, 2, 0, { STAGE_B(1, 0, t3); }, VM_NONE);
    PHASE(1, 3, 0, { STAGE_B(1, 1, t3); }, VM_4);
  }

  // ---- tail (i = 15): tiles 30 (buf0), 31 (buf1); only A(31) left to stage ----
  PHASE(0, 0, 1, { STAGE_A(1, 0, 31); }, VM_NONE);
  PHASE(0, 1, 0, { STAGE_A(1, 1, 31); }, VM_NONE);
  PHASE(0, 2, 0, {}, VM_NONE);
  PHASE(0, 3, 0, {}, VM_0);
  PHASE(1, 0, 1, {}, VM_NONE);
  PHASE(1, 1, 0, {}, VM_NONE);
  PHASE(1, 2, 0, {}, VM_NONE);
  PHASE(1, 3, 0, {}, VM_NONE);

  // ---- fused LSTM epilogue ----
  // C/D layout: col = lane&15 (actual n), row = (lane>>4)*4 + reg (batch m)
  {
    const int n = n0 + wn * 16 + lrow;
    const float b0 = bias[n];
    const float b1 = bias[N_GATE + n];
    const float b2 = bias[2 * N_GATE + n];
    const float b3 = bias[3 * N_GATE + n];
    const size_t base = (size_t)(m0 + wm * 128 + lk * 4) * N_GATE + n;
#pragma unroll
    for (int mi = 0; mi < 8; ++mi) {
#pragma unroll
      for (int r = 0; r < 4; ++r) {
        const size_t off = base + (size_t)(mi * 16 + r) * N_GATE;
        const float fg = fast_sigmoid(acc[mi][0][r] + b0);
        const float ig = fast_sigmoid(acc[mi][1][r] + b1);
        const float og = fast_sigmoid(acc[mi][2][r] + b2);
        const float sg = fast_sigmoid(acc[mi][3][r] + b3);
        const float cn = fg * cell[off] + ig * sg;
        outC[off] = cn;
        outH[off] = og * fast_tanh(cn);
      }
    }
  }
}

extern "C" void kernel_launch(void* const* d_in, const int* in_sizes, int n_in,
                              void* d_out, int out_size, void* d_ws, size_t ws_size,
                              hipStream_t stream) {
  const float* inp  = (const float*)d_in[0];
  // d_in[1] = hidden: UNUSED by the reference computation
  const float* cell = (const float*)d_in[2];
  const float* W    = (const float*)d_in[3];
  const float* bias = (const float*)d_in[4];

  float* outH = (float*)d_out;
  float* outC = (float*)d_out + (size_t)B_ROWS * N_GATE;

  short* Abf = (short*)d_ws;                           // 32 MiB
  short* Wt  = (short*)d_ws + (size_t)B_ROWS * K_DIM;  // 32 MiB

  // 1) input -> bf16
  {
    int n8 = (B_ROWS * K_DIM) / 8;
    convert_in_kernel<<<2048, 256, 0, stream>>>((const float4*)inp,
                                                (s16x8*)Abf, n8);
  }
  // 2) W -> Wt (transpose + bf16)
  {
    dim3 grid(W_COLS / 64, K_DIM / 64);
    convert_w_kernel<<<grid, 256, 0, stream>>>(W, Wt);
  }
  // 3) fused GEMM + gates (128 KiB dynamic LDS)
  {
    (void)hipFuncSetAttribute(reinterpret_cast<const void*>(&lstm_gemm_kernel),
                              hipFuncAttributeMaxDynamicSharedMemorySize, 131072);
    int nblocks = (B_ROWS / BM) * (N_GATE / 64);  // 32 * 32 = 1024
    lstm_gemm_kernel<<<nblocks, 512, 131072, stream>>>(Abf, Wt, bias, cell,
                                                       outH, outC);
  }
}

// Round 7
// 534.204 us; speedup vs baseline: 1.1410x; 1.0049x over previous
//
#include <hip/hip_runtime.h>
#include <cstddef>
#include <cstdint>

// ---- problem constants ----
#define B_ROWS 8192   // batch
#define K_DIM  2048   // IN_CH
#define N_GATE 2048   // OUT_CH (per gate)
#define NG     4      // gates: f, i, o, s
#define W_COLS (NG * N_GATE)  // 8192

// ---- GEMM tile config ----
#define BM   256      // batch rows per block
#define BK   64       // K per tile
#define NTIL 32       // K_DIM / BK

typedef __attribute__((ext_vector_type(8))) short s16x8;   // 8 bf16
typedef __attribute__((ext_vector_type(4))) float f32x4;

__device__ __forceinline__ float fast_sigmoid(float x) {
  return 1.0f / (1.0f + __expf(-x));
}
__device__ __forceinline__ float fast_tanh(float x) {
  return 1.0f - 2.0f / (__expf(2.0f * x) + 1.0f);
}

// ---------------- prep kernel 1: input f32 -> bf16 (16B stores) ----------------
__global__ void convert_in_kernel(const float4* __restrict__ src,
                                  s16x8* __restrict__ dst, int n8) {
  int idx = blockIdx.x * blockDim.x + threadIdx.x;
  int stride = gridDim.x * blockDim.x;
  for (int i = idx; i < n8; i += stride) {
    float4 a = src[2 * i], b = src[2 * i + 1];
    s16x8 o = { __builtin_bit_cast(short, (__bf16)a.x),
                __builtin_bit_cast(short, (__bf16)a.y),
                __builtin_bit_cast(short, (__bf16)a.z),
                __builtin_bit_cast(short, (__bf16)a.w),
                __builtin_bit_cast(short, (__bf16)b.x),
                __builtin_bit_cast(short, (__bf16)b.y),
                __builtin_bit_cast(short, (__bf16)b.z),
                __builtin_bit_cast(short, (__bf16)b.w) };
    dst[i] = o;
  }
}

// ---------------- prep kernel 2: W [K][4N] f32 -> Wt [4N][K] bf16 ----------------
// (unchanged from measured round-6 kernel — prep is next round's target)
__device__ __forceinline__ unsigned int pack2bf16(float x, float y) {
  unsigned short lo = __builtin_bit_cast(unsigned short, (__bf16)x);
  unsigned short hi = __builtin_bit_cast(unsigned short, (__bf16)y);
  return ((unsigned int)hi << 16) | lo;
}

__global__ __launch_bounds__(256) void convert_w_kernel(const float* __restrict__ W,
                                                        short* __restrict__ Wt) {
  __shared__ unsigned int tile[64 * 32];  // 8 KiB
  const int t = threadIdx.x;
  const int n0 = blockIdx.x * 64;   // along 8192 gate-cols
  const int k0 = blockIdx.y * 64;   // along 2048 K
  {
    const int kr = t >> 2, seg = t & 3;
    const float4* src = (const float4*)(W + (size_t)(k0 + kr) * W_COLS + n0 + seg * 16);
#pragma unroll
    for (int u = 0; u < 4; ++u) {
      float4 v = src[u];
      const int np = seg * 8 + u * 2;
      tile[kr * 32 + (np ^ (kr & 31))]       = pack2bf16(v.x, v.y);
      tile[kr * 32 + ((np + 1) ^ (kr & 31))] = pack2bf16(v.z, v.w);
    }
  }
  __syncthreads();
  {
    const int np = t >> 3;   // column pair 0..31 -> output rows n0+2np, +1
    const int kb = t & 7;    // k-block of 8
    unsigned int w[8];
#pragma unroll
    for (int v = 0; v < 8; ++v) {
      const int k = kb * 8 + v;
      w[v] = tile[k * 32 + (np ^ (k & 31))];
    }
    s16x8 lo, hi;
#pragma unroll
    for (int v = 0; v < 8; ++v) {
      lo[v] = (short)(w[v] & 0xffff);
      hi[v] = (short)(w[v] >> 16);
    }
    short* d0 = Wt + (size_t)(n0 + 2 * np) * K_DIM + k0 + kb * 8;
    *(s16x8*)d0 = lo;
    *(s16x8*)(d0 + K_DIM) = hi;
  }
}

// ---------------- main fused GEMM + LSTM epilogue ----------------
// Round-7 change vs measured round-6 (285 µs, MfmaUtil 42%): A TRIPLE-buffer.
// Diagnosis: round-6 staged A(T1) at ph1/2 and vmcnt-waited it at ph4 — only
// 2-3 phases (~250 cyc) of latency cover vs ~500-900 cyc L2/L3 latency → the
// per-K-tile vmcnt stalls explain the 2x gap to the MFMA/LDS overlap floor.
// Now: A rotates 3 buffers (tile t -> Abuf t%3), B double-buffered. Cover:
// A = 6-7 phases, B = 4-5 phases. LDS = 3*32K (A) + 2*32K (B) = 160 KiB.
//
// Iter i (tiles T0=2i buf (2i)%3 + B0, T1=2i+1 buf (2i+1)%3 + B1):
//   ph1: stage A(2i+2)h0 -> (2i+2)%3   [freed iter i-1 ph8]
//   ph2: stage A(2i+2)h1
//   ph3: stage B(2i+2)h0 -> B0         [B0 bfr-read only at ph1]
//   ph4: stage B(2i+2)h1; vmcnt(8) retires A(2i+1),B(2i+1) (read ph5+)
//   ph5: stage A(2i+3)h0 -> (2i)%3     [freed ph4]
//   ph6: stage A(2i+3)h1
//   ph7: stage B(2i+3)h0 -> B1
//   ph8: stage B(2i+3)h1; vmcnt(8) retires A(2i+2),B(2i+2) (read next ph1)
// Ledger: loop-top outstanding = 8 (next tile's A+B); peak 16; never 0 mid-loop.
// Loop unrolled x3 (buf rotation compile-time). Tail i=15: no stages,
// vmcnt(0) at ph4 drains A(31),B(31).
// 16B-granule XOR swizzle unchanged (phys = logical ^ (row&7), both-sides).
#define GL16(gsrc, ldst)                                                        \
  __builtin_amdgcn_global_load_lds(                                             \
      (const __attribute__((address_space(1))) unsigned int*)(gsrc),            \
      (__attribute__((address_space(3))) unsigned int*)(ldst), 16, 0, 0)

#define MFMA16 __builtin_amdgcn_mfma_f32_16x16x32_bf16

__global__ __launch_bounds__(512, 2) void lstm_gemm_kernel(
    const short* __restrict__ Abf,   // bf16 [8192][2048]
    const short* __restrict__ Wt,    // bf16 [8192][2048]
    const float* __restrict__ bias,  // [8192]
    const float* __restrict__ cell,  // [8192][2048]
    float* __restrict__ outH,        // [8192][2048]
    float* __restrict__ outC) {      // [8192][2048]
  extern __shared__ short lds[];  // A bufs: shorts 0,16384,32768; B: 49152,65536

  const int tid = threadIdx.x;
  const int lane = tid & 63;
  const int wid = tid >> 6;
  const int wm = wid >> 2;   // 0..1
  const int wn = wid & 3;    // 0..3
  const int lrow = lane & 15;
  const int lk = lane >> 4;  // 0..3

  // XCD-banded swizzle: XCD x owns tn in [x*4, x*4+4), tm sweeps within.
  const int bid = blockIdx.x;
  const int xcd = bid & 7, j = bid >> 3;
  const int tn = xcd * 4 + (j >> 5);  // 0..31
  const int tm = j & 31;              // 0..31
  const int m0 = tm * BM;
  const int n0 = tn * 64;

  // ---- staging sources: physical granule p = h*1024 + jj*512 + tid ----
  size_t a_src[2][2], b_src[2][2];
#pragma unroll
  for (int h = 0; h < 2; ++h)
#pragma unroll
    for (int jj = 0; jj < 2; ++jj) {
      const int p = h * 1024 + jj * 512 + tid;
      const int r = p >> 3;                 // tile row 0..255
      const int gl = (p & 7) ^ (r & 7);     // inverse swizzle on SOURCE
      a_src[h][jj] = (size_t)(m0 + r) * K_DIM + gl * 8;
      const int wn16 = r >> 6, g = (r >> 4) & 3, nc4 = r & 15;
      b_src[h][jj] = (size_t)(g * N_GATE + n0 + wn16 * 16 + nc4) * K_DIM + gl * 8;
    }

#define STAGE_A(AB, H, KT) do {                                                  \
    GL16(Abf + a_src[H][0] + (size_t)(KT) * BK,                                  \
         lds + (AB) * 16384 + ((H) * 1024 + tid) * 8);                           \
    GL16(Abf + a_src[H][1] + (size_t)(KT) * BK,                                  \
         lds + (AB) * 16384 + ((H) * 1024 + 512 + tid) * 8);                     \
  } while (0)
#define STAGE_B(BB, H, KT) do {                                                  \
    GL16(Wt + b_src[H][0] + (size_t)(KT) * BK,                                   \
         lds + 49152 + (BB) * 16384 + ((H) * 1024 + tid) * 8);                   \
    GL16(Wt + b_src[H][1] + (size_t)(KT) * BK,                                   \
         lds + 49152 + (BB) * 16384 + ((H) * 1024 + 512 + tid) * 8);             \
  } while (0)

  // ---- fragment read offsets (bytes within a buffer; granule-swizzled) ----
  const int pg0 = (lk ^ (lrow & 7)) * 16;        // kk=0 physical granule byte
  const int pg1 = ((4 + lk) ^ (lrow & 7)) * 16;  // kk=1
  const int aoff0 = (wm * 128 + lrow) * 128 + pg0;
  const int aoff1 = (wm * 128 + lrow) * 128 + pg1;
  const int boff0 = (wn * 64 + lrow) * 128 + pg0;
  const int boff1 = (wn * 64 + lrow) * 128 + pg1;
  const char* ldsb = (const char*)lds;
#define AF(AB, MI, KK) \
  (*(const s16x8*)(ldsb + (AB) * 32768 + aoff##KK + (MI) * 2048))
#define BFR(BB, G, KK) \
  (*(const s16x8*)(ldsb + 98304 + (BB) * 32768 + boff##KK + (G) * 2048))

  f32x4 acc[8][4];
#pragma unroll
  for (int mi = 0; mi < 8; ++mi)
#pragma unroll
    for (int g = 0; g < 4; ++g) acc[mi][g] = (f32x4){0.f, 0.f, 0.f, 0.f};

  s16x8 bfr[4][2];

#define MMQ(MI, A0, A1) do {                                                     \
    acc[MI][0] = MFMA16(A0, bfr[0][0], acc[MI][0], 0, 0, 0);                     \
    acc[MI][0] = MFMA16(A1, bfr[0][1], acc[MI][0], 0, 0, 0);                     \
    acc[MI][1] = MFMA16(A0, bfr[1][0], acc[MI][1], 0, 0, 0);                     \
    acc[MI][1] = MFMA16(A1, bfr[1][1], acc[MI][1], 0, 0, 0);                     \
    acc[MI][2] = MFMA16(A0, bfr[2][0], acc[MI][2], 0, 0, 0);                     \
    acc[MI][2] = MFMA16(A1, bfr[2][1], acc[MI][2], 0, 0, 0);                     \
    acc[MI][3] = MFMA16(A0, bfr[3][0], acc[MI][3], 0, 0, 0);                     \
    acc[MI][3] = MFMA16(A1, bfr[3][1], acc[MI][3], 0, 0, 0);                     \
  } while (0)

#define VM_NONE do {} while (0)
#define VM_8 asm volatile("s_waitcnt vmcnt(8)" ::: "memory")
#define VM_0 asm volatile("s_waitcnt vmcnt(0)" ::: "memory")

#define PHASE(AB, BB, Q, LOADB, STG, VM) do {                                    \
    if (LOADB) {                                                                 \
      bfr[0][0] = BFR(BB, 0, 0); bfr[0][1] = BFR(BB, 0, 1);                      \
      bfr[1][0] = BFR(BB, 1, 0); bfr[1][1] = BFR(BB, 1, 1);                      \
      bfr[2][0] = BFR(BB, 2, 0); bfr[2][1] = BFR(BB, 2, 1);                      \
      bfr[3][0] = BFR(BB, 3, 0); bfr[3][1] = BFR(BB, 3, 1);                      \
    }                                                                            \
    s16x8 af00 = AF(AB, 2 * (Q), 0), af01 = AF(AB, 2 * (Q), 1);                  \
    s16x8 af10 = AF(AB, 2 * (Q) + 1, 0), af11 = AF(AB, 2 * (Q) + 1, 1);          \
    STG;                                                                         \
    VM;                                                                          \
    __builtin_amdgcn_s_barrier();                                                \
    asm volatile("s_waitcnt lgkmcnt(0)" ::: "memory");                           \
    __builtin_amdgcn_s_setprio(1);                                               \
    MMQ(2 * (Q), af00, af01);                                                    \
    MMQ(2 * (Q) + 1, af10, af11);                                                \
    __builtin_amdgcn_s_setprio(0);                                               \
    __builtin_amdgcn_s_barrier();                                                \
  } while (0)

  // One iteration i: reads A-bufs RA0 (T0) / RA1 (T1); stages A(T2)->SA2 at
  // ph1/2, B(T2)->B0 at ph3/4 [vmcnt(8)], A(T3)->SA3 at ph5/6, B(T3)->B1 at
  // ph7/8 [vmcnt(8)].
#define ITER(RA0, RA1, SA2, SA3, T2, T3) do {                                    \
    PHASE(RA0, 0, 0, 1, { STAGE_A(SA2, 0, T2); }, VM_NONE);                      \
    PHASE(RA0, 0, 1, 0, { STAGE_A(SA2, 1, T2); }, VM_NONE);                      \
    PHASE(RA0, 0, 2, 0, { STAGE_B(0, 0, T2); }, VM_NONE);                        \
    PHASE(RA0, 0, 3, 0, { STAGE_B(0, 1, T2); }, VM_8);                           \
    PHASE(RA1, 1, 0, 1, { STAGE_A(SA3, 0, T3); }, VM_NONE);                      \
    PHASE(RA1, 1, 1, 0, { STAGE_A(SA3, 1, T3); }, VM_NONE);                      \
    PHASE(RA1, 1, 2, 0, { STAGE_B(1, 0, T3); }, VM_NONE);                        \
    PHASE(RA1, 1, 3, 0, { STAGE_B(1, 1, T3); }, VM_8);                           \
  } while (0)

  // ---- prologue: A(0)->A0, B(0)->B0, A(1)->A1, B(1)->B1 (16 loads) ----
  STAGE_A(0, 0, 0); STAGE_A(0, 1, 0);
  STAGE_B(0, 0, 0); STAGE_B(0, 1, 0);
  STAGE_A(1, 0, 1); STAGE_A(1, 1, 1);
  STAGE_B(1, 0, 1); STAGE_B(1, 1, 1);
  VM_8;  // retire tile0's A+B; tile1 (8 loads) in flight
  __builtin_amdgcn_s_barrier();

  // ---- main loop: i = 0..14, unrolled x3 for the A-buf rotation ----
  for (int o = 0; o < 5; ++o) {
    const int t = 6 * o;
    ITER(0, 1, 2, 0, t + 2, t + 3);  // i=3o:   T0 buf0, T1 buf1
    ITER(2, 0, 1, 2, t + 4, t + 5);  // i=3o+1: T0 buf2, T1 buf0
    ITER(1, 2, 0, 1, t + 6, t + 7);  // i=3o+2: T0 buf1, T1 buf2
  }

  // ---- tail (i=15): tiles 30 (buf0,B0), 31 (buf1,B1); nothing left to stage --
  PHASE(0, 0, 0, 1, {}, VM_NONE);
  PHASE(0, 0, 1, 0, {}, VM_NONE);
  PHASE(0, 0, 2, 0, {}, VM_NONE);
  PHASE(0, 0, 3, 0, {}, VM_0);   // drain A(31),B(31) before ph5 reads
  PHASE(1, 1, 0, 1, {}, VM_NONE);
  PHASE(1, 1, 1, 0, {}, VM_NONE);
  PHASE(1, 1, 2, 0, {}, VM_NONE);
  PHASE(1, 1, 3, 0, {}, VM_NONE);

  // ---- fused LSTM epilogue ----
  // C/D layout: col = lane&15 (actual n), row = (lane>>4)*4 + reg (batch m)
  {
    const int n = n0 + wn * 16 + lrow;
    const float b0 = bias[n];
    const float b1 = bias[N_GATE + n];
    const float b2 = bias[2 * N_GATE + n];
    const float b3 = bias[3 * N_GATE + n];
    const size_t base = (size_t)(m0 + wm * 128 + lk * 4) * N_GATE + n;
#pragma unroll
    for (int mi = 0; mi < 8; ++mi) {
#pragma unroll
      for (int r = 0; r < 4; ++r) {
        const size_t off = base + (size_t)(mi * 16 + r) * N_GATE;
        const float fg = fast_sigmoid(acc[mi][0][r] + b0);
        const float ig = fast_sigmoid(acc[mi][1][r] + b1);
        const float og = fast_sigmoid(acc[mi][2][r] + b2);
        const float sg = fast_sigmoid(acc[mi][3][r] + b3);
        const float cn = fg * cell[off] + ig * sg;
        outC[off] = cn;
        outH[off] = og * fast_tanh(cn);
      }
    }
  }
}

extern "C" void kernel_launch(void* const* d_in, const int* in_sizes, int n_in,
                              void* d_out, int out_size, void* d_ws, size_t ws_size,
                              hipStream_t stream) {
  const float* inp  = (const float*)d_in[0];
  // d_in[1] = hidden: UNUSED by the reference computation
  const float* cell = (const float*)d_in[2];
  const float* W    = (const float*)d_in[3];
  const float* bias = (const float*)d_in[4];

  float* outH = (float*)d_out;
  float* outC = (float*)d_out + (size_t)B_ROWS * N_GATE;

  short* Abf = (short*)d_ws;                           // 32 MiB
  short* Wt  = (short*)d_ws + (size_t)B_ROWS * K_DIM;  // 32 MiB

  // 1) input -> bf16
  {
    int n8 = (B_ROWS * K_DIM) / 8;
    convert_in_kernel<<<2048, 256, 0, stream>>>((const float4*)inp,
                                                (s16x8*)Abf, n8);
  }
  // 2) W -> Wt (transpose + bf16)
  {
    dim3 grid(W_COLS / 64, K_DIM / 64);
    convert_w_kernel<<<grid, 256, 0, stream>>>(W, Wt);
  }
  // 3) fused GEMM + gates (160 KiB dynamic LDS)
  {
    (void)hipFuncSetAttribute(reinterpret_cast<const void*>(&lstm_gemm_kernel),
                              hipFuncAttributeMaxDynamicSharedMemorySize, 163840);
    int nblocks = (B_ROWS / BM) * (N_GATE / 64);  // 32 * 32 = 1024
    lstm_gemm_kernel<<<nblocks, 512, 163840, stream>>>(Abf, Wt, bias, cell,
                                                       outH, outC);
  }
}